// Round 9
// baseline (434.452 us; speedup 1.0000x reference)
//
#include <hip/hip_runtime.h>
#include <hip/hip_bf16.h>
#include <hip/hip_cooperative_groups.h>

namespace cg = cooperative_groups;

// GraphAttentionEncoder: 2x GATConv (shared edges) + gated mix + residual + LN
// N=50000, DIM=128, H=4, C=32, E=800000 (+N self loops)
//
// R8 changes vs R7:
//  - R7's coop launch almost certainly FAILED silently (absmax 0.719 ==
//    "k_agg over poisoned CSR" == mega never ran). Now: occupancy-query
//    clamps the coop grid, the launch error is checked, and on any failure
//    we fall back to the R6-proven 5-kernel path. Phase bodies are shared
//    __device__ functions so both paths run identical code.
//  - k_agg unchanged (R6-validated, 66us).

typedef unsigned short u16;
typedef __bf16 bf16x8 __attribute__((ext_vector_type(8)));
typedef float f32x4 __attribute__((ext_vector_type(4)));

#define LRELU_SLOPE 0.2f
#define LN_EPS 1e-5f
#define SH 8                 // atomic shards

__device__ __forceinline__ float bfbits(unsigned int hi_bits) {
    union { unsigned int i; float f; } v; v.i = hi_bits; return v.f;
}
__device__ __forceinline__ float bflo(unsigned int u) { return bfbits(u << 16); }
__device__ __forceinline__ float bfhi(unsigned int u) { return bfbits(u & 0xFFFF0000u); }
__device__ __forceinline__ u16 f2bf(float f) {
    union { float f; unsigned int i; } v; v.f = f;
    unsigned int lsb = (v.i >> 16) & 1u;
    v.i += 0x7FFFu + lsb;                 // round-to-nearest-even
    return (u16)(v.i >> 16);
}

// ================= shared phase bodies =================

// wb[col][k] = W[k][col] bf16 (col 0-127 -> W1, 128-255 -> W2)
__device__ __forceinline__ void ph_wb(int i, const float* __restrict__ W1,
                                      const float* __restrict__ W2,
                                      u16* __restrict__ wb) {
    int col = i >> 7, k = i & 127;
    float v = (col < 128) ? W1[k * 128 + col] : W2[k * 128 + (col - 128)];
    wb[i] = f2bf(v);
}

// one 64-row MFMA GEMM tile; output hbp[row][c] = (h2[c]<<16)|h1[c]
__device__ __forceinline__ void ph_gemm(int t0, int tid, const float* __restrict__ x,
                                        const u16* __restrict__ wb,
                                        unsigned int* __restrict__ hbp, int n) {
    int wave = tid >> 6, lane = tid & 63;
    int quad = lane >> 4, r16 = lane & 15;
    int row = t0 * 64 + wave * 16 + r16;
    int arow = (row < n) ? row : n - 1;
    const float* xp = x + (size_t)arow * 128 + quad * 8;
    union { u16 u[8]; bf16x8 b; } ar;
    bf16x8 af[4];
#pragma unroll
    for (int ks = 0; ks < 4; ks++) {
        float4 lo = *(const float4*)(xp + ks * 32);
        float4 hi = *(const float4*)(xp + ks * 32 + 4);
        ar.u[0] = f2bf(lo.x); ar.u[1] = f2bf(lo.y); ar.u[2] = f2bf(lo.z); ar.u[3] = f2bf(lo.w);
        ar.u[4] = f2bf(hi.x); ar.u[5] = f2bf(hi.y); ar.u[6] = f2bf(hi.z); ar.u[7] = f2bf(hi.w);
        af[ks] = ar.b;
    }
    f32x4 acc[16];
#pragma unroll
    for (int t = 0; t < 16; t++) acc[t] = (f32x4){0.f, 0.f, 0.f, 0.f};
    const u16* bbase = wb + r16 * 128 + quad * 8;
#pragma unroll
    for (int t = 0; t < 16; t++) {
        const u16* bptr = bbase + t * 2048;
#pragma unroll
        for (int ks = 0; ks < 4; ks++) {
            bf16x8 b = *(const bf16x8*)(bptr + ks * 32);
            acc[t] = __builtin_amdgcn_mfma_f32_16x16x32_bf16(af[ks], b, acc[t], 0, 0, 0);
        }
    }
    int row0 = t0 * 64 + wave * 16 + quad * 4;
#pragma unroll
    for (int t = 0; t < 8; t++) {
        int c = t * 16 + r16;
#pragma unroll
        for (int g = 0; g < 4; g++) {
            int gr = row0 + g;
            if (gr < n) {
                unsigned int pv = ((unsigned int)f2bf(acc[t + 8][g]) << 16) | f2bf(acc[t][g]);
                hbp[(size_t)gr * 128 + c] = pv;
            }
        }
    }
}

// logits for item i = node*4+head; es/ed rows [node][8], slot = layer*4+head
__device__ __forceinline__ void ph_logits(int i, const unsigned int* __restrict__ hbp,
                                          const float* __restrict__ as1,
                                          const float* __restrict__ ad1,
                                          const float* __restrict__ as2,
                                          const float* __restrict__ ad2,
                                          float* __restrict__ es, float* __restrict__ ed) {
    int node = i >> 2, head = i & 3;
    const uint4* hv = (const uint4*)(hbp + (size_t)node * 128 + head * 32);
    const float* a1 = as1 + head * 32;
    const float* d1 = ad1 + head * 32;
    const float* a2 = as2 + head * 32;
    const float* d2 = ad2 + head * 32;
    float s1 = 0.f, t1 = 0.f, s2 = 0.f, t2 = 0.f;
#pragma unroll
    for (int q = 0; q < 8; q++) {
        uint4 wv = hv[q];
        unsigned int ws[4] = {wv.x, wv.y, wv.z, wv.w};
#pragma unroll
        for (int h = 0; h < 4; h++) {
            int c = q * 4 + h;
            float v1 = bflo(ws[h]), v2 = bfhi(ws[h]);
            s1 += v1 * a1[c]; t1 += v1 * d1[c];
            s2 += v2 * a2[c]; t2 += v2 * d2[c];
        }
    }
    es[node * 8 + head]     = s1;
    ed[node * 8 + head]     = t1;
    es[node * 8 + 4 + head] = s2;
    ed[node * 8 + 4 + head] = t2;
}

// block-sum of total degree for 256-node tile b
__device__ __forceinline__ void ph_bsum(int b, int tid, const int* __restrict__ deg8,
                                        int* __restrict__ bsum, int n, int* s) {
    int i = b * 256 + tid;
    int v = 0;
    if (i < n) {
#pragma unroll
        for (int x = 0; x < SH; x++) v += deg8[x * n + i];
    }
    s[tid] = v;
    __syncthreads();
    for (int o = 128; o; o >>= 1) {
        if (tid < o) s[tid] += s[tid + o];
        __syncthreads();
    }
    if (tid == 0) bsum[b] = s[0];
    __syncthreads();
}

// scan tile b: offs + convert deg8 in place to per-shard cursors
__device__ __forceinline__ void ph_scan(int b, int tid, int* __restrict__ deg8,
                                        const int* __restrict__ bsum,
                                        int* __restrict__ offs, int nb, int n,
                                        int* s, int* bp) {
    int bv = (tid < nb) ? bsum[tid] : 0;
    s[tid] = bv;
    __syncthreads();
    for (int o = 1; o < 256; o <<= 1) {
        int u = (tid >= o) ? s[tid - o] : 0;
        __syncthreads();
        s[tid] += u;
        __syncthreads();
    }
    if (tid == b) *bp = s[tid] - bv;      // exclusive prefix of tile b
    __syncthreads();
    int i = b * 256 + tid;
    int d[SH];
    int v = 0;
    if (i < n) {
#pragma unroll
        for (int x = 0; x < SH; x++) { d[x] = deg8[x * n + i]; v += d[x]; }
    }
    s[tid] = v;
    __syncthreads();
    for (int o = 1; o < 256; o <<= 1) {
        int u = (tid >= o) ? s[tid - o] : 0;
        __syncthreads();
        s[tid] += u;
        __syncthreads();
    }
    if (i < n) {
        int e = *bp + s[tid] - v;
        offs[i] = e;
        int run = e;
#pragma unroll
        for (int x = 0; x < SH; x++) { deg8[x * n + i] = run; run += d[x]; }
        if (i == n - 1) offs[n] = e + v;
    }
    __syncthreads();
}

// counting sort + per-edge weights for edge i
__device__ __forceinline__ void ph_fill(int i, const int* __restrict__ ei,
                                        int* __restrict__ cursor8,
                                        const float* __restrict__ es,
                                        const float* __restrict__ ed,
                                        int* __restrict__ ssrc, uint4* __restrict__ w,
                                        int E, int n) {
    int sv = ei[i], d = ei[E + i];
    int sh = (i >> 8) & (SH - 1);
    int pos = atomicAdd(&cursor8[sh * n + d], 1);
    ssrc[pos] = sv;
    float4 eslo = *(const float4*)(es + sv * 8);
    float4 eshi = *(const float4*)(es + sv * 8 + 4);
    float4 edlo = *(const float4*)(ed + d * 8);
    float4 edhi = *(const float4*)(ed + d * 8 + 4);
    float e1[4] = {eslo.x + edlo.x, eslo.y + edlo.y, eslo.z + edlo.z, eslo.w + edlo.w};
    float e2[4] = {eshi.x + edhi.x, eshi.y + edhi.y, eshi.z + edhi.z, eshi.w + edhi.w};
    unsigned int uw[4];
#pragma unroll
    for (int h = 0; h < 4; h++) {
        float av = e1[h]; av = (av > 0.f) ? av : LRELU_SLOPE * av;
        float bv = e2[h]; bv = (bv > 0.f) ? bv : LRELU_SLOPE * bv;
        uw[h] = ((unsigned int)f2bf(__expf(bv)) << 16) | f2bf(__expf(av));
    }
    w[pos] = make_uint4(uw[0], uw[1], uw[2], uw[3]);
}

// ================= cooperative mega kernel =================

struct MegaArgs {
    const float* x;
    const int* ei;
    const float* W1; const float* W2;
    const float* as1; const float* ad1;
    const float* as2; const float* ad2;
    u16* wb;
    unsigned int* hbp;
    float* es; float* ed;
    int* deg8;              // becomes cursor8 after scan
    int* offs;
    int* bsum;
    int* ssrc;
    uint4* w;
    int n, E, Gg, nb;
};

__global__ __launch_bounds__(256, 2) void k_mega(MegaArgs a) {
    cg::grid_group grid = cg::this_grid();
    __shared__ int s[256];
    __shared__ int bp;
    const int G = gridDim.x;
    const int bid = blockIdx.x, tid = threadIdx.x;
    const int gtid = bid * 256 + tid, gstride = G * 256;
    const int n = a.n, E = a.E;

    for (int i = gtid; i < 32768; i += gstride) ph_wb(i, a.W1, a.W2, a.wb);
    for (int i = gtid; i < SH * n; i += gstride) a.deg8[i] = 0;
    grid.sync();

    for (int t0 = bid; t0 < a.Gg; t0 += G) ph_gemm(t0, tid, a.x, a.wb, a.hbp, n);
    for (int i = gtid; i < E; i += gstride) {
        int sh = (i >> 8) & (SH - 1);
        atomicAdd(&a.deg8[sh * n + a.ei[E + i]], 1);
    }
    grid.sync();

    for (int i = gtid; i < n * 4; i += gstride)
        ph_logits(i, a.hbp, a.as1, a.ad1, a.as2, a.ad2, a.es, a.ed);
    for (int b = bid; b < a.nb; b += G) ph_bsum(b, tid, a.deg8, a.bsum, n, s);
    grid.sync();

    for (int b = bid; b < a.nb; b += G)
        ph_scan(b, tid, a.deg8, a.bsum, a.offs, a.nb, n, s, &bp);
    grid.sync();

    for (int i = gtid; i < E; i += gstride)
        ph_fill(i, a.ei, a.deg8, a.es, a.ed, a.ssrc, a.w, E, n);
}

// ================= fallback (R6-proven) kernels =================

__global__ void k_prep(const float* __restrict__ W1, const float* __restrict__ W2,
                       u16* __restrict__ wb, int* __restrict__ deg8, int n) {
    int i = blockIdx.x * 256 + threadIdx.x;
    if (i < 32768) ph_wb(i, W1, W2, wb);
    if (i < n) {
#pragma unroll
        for (int x = 0; x < SH; x++) deg8[x * n + i] = 0;
    }
}

__global__ __launch_bounds__(256) void k_cg(const float* __restrict__ x,
                                            const u16* __restrict__ wb,
                                            unsigned int* __restrict__ hbp, int n,
                                            const int* __restrict__ ei,
                                            int* __restrict__ deg8, int E, int Gg) {
    if ((int)blockIdx.x >= Gg) {
        int i = ((int)blockIdx.x - Gg) * 256 + threadIdx.x;
        if (i < E) {
            int sh = (i >> 8) & (SH - 1);
            atomicAdd(&deg8[sh * n + ei[E + i]], 1);
        }
        return;
    }
    ph_gemm(blockIdx.x, threadIdx.x, x, wb, hbp, n);
}

__global__ void k_lb(const unsigned int* __restrict__ hbp,
                     const float* __restrict__ as1, const float* __restrict__ ad1,
                     const float* __restrict__ as2, const float* __restrict__ ad2,
                     float* __restrict__ es, float* __restrict__ ed, int n,
                     const int* __restrict__ deg8, int* __restrict__ bsum, int Gl) {
    __shared__ int s[256];
    if ((int)blockIdx.x >= Gl) {
        ph_bsum((int)blockIdx.x - Gl, threadIdx.x, deg8, bsum, n, s);
        return;
    }
    int i = blockIdx.x * 256 + threadIdx.x;
    if (i < n * 4) ph_logits(i, hbp, as1, ad1, as2, ad2, es, ed);
}

__global__ void k_scan(int* __restrict__ deg8, const int* __restrict__ bsum,
                       int* __restrict__ offs, int nb, int n) {
    __shared__ int s[256];
    __shared__ int bp;
    ph_scan(blockIdx.x, threadIdx.x, deg8, bsum, offs, nb, n, s, &bp);
}

__global__ void k_fill(const int* __restrict__ ei, int* __restrict__ cursor8,
                       const float* __restrict__ es, const float* __restrict__ ed,
                       int* __restrict__ ssrc, uint4* __restrict__ w, int E, int n) {
    int i = blockIdx.x * 256 + threadIdx.x;
    if (i < E) ph_fill(i, ei, cursor8, es, ed, ssrc, w, E, n);
}

// ================= aggregation (unchanged, R6-validated) =================

__device__ __forceinline__ float wred(float v) {
#pragma unroll
    for (int off = 32; off; off >>= 1) v += __shfl_xor(v, off, 64);
    return v;
}

__device__ __forceinline__ unsigned int hsel(uint4 w, int head) {
    unsigned int r = (head == 0) ? w.x : (head == 1) ? w.y : (head == 2) ? w.z : w.w;
    return r;
}

__global__ __launch_bounds__(256) void k_agg(
    const int* __restrict__ offs, const int* __restrict__ ssrc,
    const unsigned int* __restrict__ hbp, const uint4* __restrict__ w4,
    const float* __restrict__ es, const float* __restrict__ ed,
    const float* __restrict__ b1, const float* __restrict__ b2,
    const float* __restrict__ gW, const float* __restrict__ gb,
    const float* __restrict__ x, const float* __restrict__ gamma,
    const float* __restrict__ beta, float* __restrict__ out, int n) {
    int wave = threadIdx.x >> 6, lane = threadIdx.x & 63;
    int node = blockIdx.x * 4 + wave;
    if (node >= n) return;
    node = __builtin_amdgcn_readfirstlane(node);   // wave-uniform -> s_loads

    int ca = lane * 2, cb = ca + 1;
    int head = lane >> 4;                  // = ca>>5

    // self-loop term
    const float* esp = es + node * 8;
    const float* edp = ed + node * 8;
    float e1s = esp[head] + edp[head];
    float e2s = esp[4 + head] + edp[4 + head];
    e1s = (e1s > 0.f) ? e1s : LRELU_SLOPE * e1s;
    e2s = (e2s > 0.f) ? e2s : LRELU_SLOPE * e2s;
    float w1s = __expf(e1s), w2s = __expf(e2s);
    uint2 qs = *(const uint2*)(hbp + (size_t)node * 128 + ca);
    float l1 = w1s, l2 = w2s;
    float a1a = w1s * bflo(qs.x), a1b = w1s * bflo(qs.y);
    float a2a = w2s * bfhi(qs.x), a2b = w2s * bfhi(qs.y);

    int beg = offs[node], end = offs[node + 1];
    int k = beg;
#define ACC(wp, q) { \
        float ww1 = bflo(wp), ww2 = bfhi(wp); \
        l1 += ww1; l2 += ww2; \
        a1a += ww1 * bflo(q.x); a1b += ww1 * bflo(q.y); \
        a2a += ww2 * bfhi(q.x); a2b += ww2 * bfhi(q.y); }
    for (; k + 3 < end; k += 4) {
        int j0 = ssrc[k], j1 = ssrc[k + 1], j2 = ssrc[k + 2], j3 = ssrc[k + 3];
        uint4 w0 = w4[k], w1v = w4[k + 1], w2v = w4[k + 2], w3v = w4[k + 3];
        uint2 q0 = *(const uint2*)(hbp + (size_t)j0 * 128 + ca);
        uint2 q1 = *(const uint2*)(hbp + (size_t)j1 * 128 + ca);
        uint2 q2 = *(const uint2*)(hbp + (size_t)j2 * 128 + ca);
        uint2 q3 = *(const uint2*)(hbp + (size_t)j3 * 128 + ca);
        unsigned int wp0 = hsel(w0, head), wp1 = hsel(w1v, head);
        unsigned int wp2 = hsel(w2v, head), wp3 = hsel(w3v, head);
        ACC(wp0, q0) ACC(wp1, q1) ACC(wp2, q2) ACC(wp3, q3)
    }
    for (; k < end; k++) {
        int j = ssrc[k];
        uint4 wv = w4[k];
        uint2 q = *(const uint2*)(hbp + (size_t)j * 128 + ca);
        unsigned int wp = hsel(wv, head);
        ACC(wp, q)
    }
#undef ACC

    float2 b1v = *(const float2*)(b1 + ca);
    float2 b2v = *(const float2*)(b2 + ca);
    float r1 = 1.f / l1, r2 = 1.f / l2;
    float o1a = a1a * r1 + b1v.x;
    float o1b = a1b * r1 + b1v.y;
    float o2a = a2a * r2 + b2v.x;
    float o2b = a2b * r2 + b2v.y;

    // gate logits: concat(out1,out2) @ gate_W(256x2) + gate_b
    float2 g1a = *(const float2*)(gW + 2 * ca);          // rows ca,cb
    float2 g1b = *(const float2*)(gW + 2 * cb);
    float2 g2a = *(const float2*)(gW + 2 * (128 + ca));
    float2 g2b = *(const float2*)(gW + 2 * (128 + cb));
    float p0 = o1a * g1a.x + o1b * g1b.x + o2a * g2a.x + o2b * g2b.x;
    float p1 = o1a * g1a.y + o1b * g1b.y + o2a * g2a.y + o2b * g2b.y;
    p0 = wred(p0) + gb[0];
    p1 = wred(p1) + gb[1];
    float mg = fmaxf(p0, p1);
    float eg0 = __expf(p0 - mg), eg1 = __expf(p1 - mg);
    float g0 = eg0 / (eg0 + eg1), g1 = 1.f - g0;

    float2 xv = *(const float2*)(x + (size_t)node * 128 + ca);
    float ya = xv.x + g0 * o1a + g1 * o2a;
    float yb = xv.y + g0 * o1b + g1 * o2b;

    float sm = wred(ya + yb);
    float ss = wred(ya * ya + yb * yb);
    float mean = sm * (1.f / 128.f);
    float var  = ss * (1.f / 128.f) - mean * mean;
    float rstd = rsqrtf(var + LN_EPS);
    float2 gv = *(const float2*)(gamma + ca);
    float2 bv = *(const float2*)(beta + ca);
    float2 ov;
    ov.x = (ya - mean) * rstd * gv.x + bv.x;
    ov.y = (yb - mean) * rstd * gv.y + bv.y;
    *(float2*)(out + (size_t)node * 128 + ca) = ov;
}

extern "C" void kernel_launch(void* const* d_in, const int* in_sizes, int n_in,
                              void* d_out, int out_size, void* d_ws, size_t ws_size,
                              hipStream_t stream) {
    const float* x   = (const float*)d_in[0];
    const int*   ei  = (const int*)d_in[1];
    const float* W1  = (const float*)d_in[2];
    const float* b1  = (const float*)d_in[3];
    const float* as1 = (const float*)d_in[4];
    const float* ad1 = (const float*)d_in[5];
    const float* W2  = (const float*)d_in[6];
    const float* b2  = (const float*)d_in[7];
    const float* as2 = (const float*)d_in[8];
    const float* ad2 = (const float*)d_in[9];
    const float* gW  = (const float*)d_in[10];
    const float* gb  = (const float*)d_in[11];
    const float* gamma = (const float*)d_in[12];
    const float* beta  = (const float*)d_in[13];
    float* out = (float*)d_out;

    int n = in_sizes[0] / 128;
    int E = in_sizes[1] / 2;

    char* p = (char*)d_ws;
    auto take = [&](size_t bytes) {
        char* q = p;
        p += (bytes + 255) & ~(size_t)255;
        return (void*)q;
    };
    u16* wb    = (u16*)take((size_t)256 * 128 * 2);
    unsigned int* hbp = (unsigned int*)take((size_t)n * 128 * 4);
    float* es  = (float*)take((size_t)n * 8 * 4);
    float* ed  = (float*)take((size_t)n * 8 * 4);
    int* deg8  = (int*)take((size_t)SH * n * 4);   // becomes cursor8 after scan
    int* offs  = (int*)take((size_t)(n + 1) * 4);
    int* bsum  = (int*)take((size_t)256 * 4);
    int* ssrc  = (int*)take((size_t)E * 4);
    uint4* w   = (uint4*)take((size_t)E * 16);

    int nb = (n + 255) / 256;       // 196 (<= 256 required by scan)
    int Gg = (n + 63) / 64;
    int Gc = (E + 255) / 256;
    int Gl = (n * 4 + 255) / 256;

    MegaArgs a;
    a.x = x; a.ei = ei; a.W1 = W1; a.W2 = W2;
    a.as1 = as1; a.ad1 = ad1; a.as2 = as2; a.ad2 = ad2;
    a.wb = wb; a.hbp = hbp; a.es = es; a.ed = ed;
    a.deg8 = deg8; a.offs = offs; a.bsum = bsum; a.ssrc = ssrc; a.w = w;
    a.n = n; a.E = E; a.Gg = Gg; a.nb = nb;

    // coop grid sized to queried occupancy (256 CUs on MI355X), capped at 512
    int maxB = 0;
    hipError_t qerr = hipOccupancyMaxActiveBlocksPerMultiprocessor(
        &maxB, (const void*)k_mega, 256, 0);
    hipError_t lerr = hipErrorUnknown;
    if (qerr == hipSuccess && maxB > 0) {
        int G = maxB * 256;
        if (G > 512) G = 512;
        void* params[] = { &a };
        lerr = hipLaunchCooperativeKernel((const void*)k_mega, dim3(G), dim3(256),
                                          params, 0, stream);
    }
    if (lerr != hipSuccess) {
        // fallback: R6-proven 5-kernel path (identical phase bodies)
        k_prep<<<nb, 256, 0, stream>>>(W1, W2, wb, deg8, n);
        k_cg<<<Gg + Gc, 256, 0, stream>>>(x, wb, hbp, n, ei, deg8, E, Gg);
        k_lb<<<Gl + nb, 256, 0, stream>>>(hbp, as1, ad1, as2, ad2, es, ed, n,
                                          deg8, bsum, Gl);
        k_scan<<<nb, 256, 0, stream>>>(deg8, bsum, offs, nb, n);
        k_fill<<<Gc, 256, 0, stream>>>(ei, deg8, es, ed, ssrc, w, E, n);
    }
    k_agg<<<(n + 3) / 4, 256, 0, stream>>>(offs, ssrc, hbp, w, es, ed,
                                           b1, b2, gW, gb, x, gamma, beta, out, n);
}